// Round 1
// baseline (550.393 us; speedup 1.0000x reference)
//
#include <hip/hip_runtime.h>
#include <math.h>

// Problem constants (from reference)
constexpr int NODES = 100000;
constexpr int F = 64;      // features
constexpr int C = 40;      // classes
// edges derived at launch from in_sizes[1]/2

// ---------------------------------------------------------------------------
// Phase 1: edge scatter. One wave (64 lanes) per edge; lane = feature index.
// Coalesced 256B gather of x[src], coalesced atomic region agg[dst*64..+63].
// ---------------------------------------------------------------------------
__global__ __launch_bounds__(256)
void scatter_kernel(const float* __restrict__ x,
                    const int* __restrict__ src,
                    const int* __restrict__ dst,
                    float* __restrict__ aggsum,
                    float* __restrict__ deg,
                    int nedges) {
    int lane = threadIdx.x & 63;
    int e = blockIdx.x * 4 + (threadIdx.x >> 6);   // 4 waves per block
    if (e >= nedges) return;
    int s = src[e];
    int d = dst[e];
    if ((unsigned)s >= (unsigned)NODES || (unsigned)d >= (unsigned)NODES) return;
    float v = x[(size_t)s * F + lane];
    atomicAdd(&aggsum[(size_t)d * F + lane], v);
    if (lane == 0) atomicAdd(&deg[d], 1.0f);
}

// ---------------------------------------------------------------------------
// Phase 2: per-node  out = (agg_sum/deg) @ Wl + b + x @ Wr, then log_softmax.
// One thread per node; weights staged in LDS, read as float4 (ds_read_b128,
// wave-uniform address -> broadcast, no bank conflicts).
// ---------------------------------------------------------------------------
__global__ __launch_bounds__(256)
void node_kernel(const float* __restrict__ x,
                 const float* __restrict__ aggsum,
                 const float* __restrict__ deg,
                 const float* __restrict__ wl,
                 const float* __restrict__ bl,
                 const float* __restrict__ wr,
                 float* __restrict__ out) {
    __shared__ alignas(16) float sWl[F * C];
    __shared__ alignas(16) float sWr[F * C];
    __shared__ alignas(16) float sb[C];

    for (int i = threadIdx.x; i < F * C; i += 256) {
        sWl[i] = wl[i];
        sWr[i] = wr[i];
    }
    if (threadIdx.x < C) sb[threadIdx.x] = bl[threadIdx.x];
    __syncthreads();

    int n = blockIdx.x * 256 + threadIdx.x;
    if (n >= NODES) return;

    float inv = 1.0f / fmaxf(deg[n], 1.0f);

    float4 acc[10];  // 40 class accumulators
    const float4* sb4 = (const float4*)sb;
#pragma unroll
    for (int q = 0; q < 10; ++q) acc[q] = sb4[q];

    const float4* xr  = (const float4*)(x      + (size_t)n * F);
    const float4* ar  = (const float4*)(aggsum + (size_t)n * F);
    const float4* wl4 = (const float4*)sWl;
    const float4* wr4 = (const float4*)sWr;

    for (int f4 = 0; f4 < F / 4; ++f4) {
        float4 xv = xr[f4];
        float4 av = ar[f4];
        float xs[4] = {xv.x, xv.y, xv.z, xv.w};
        float as_[4] = {av.x * inv, av.y * inv, av.z * inv, av.w * inv};
#pragma unroll
        for (int j = 0; j < 4; ++j) {
            int f = f4 * 4 + j;
            float xf = xs[j];
            float af = as_[j];
#pragma unroll
            for (int q = 0; q < 10; ++q) {
                float4 wlv = wl4[f * 10 + q];
                float4 wrv = wr4[f * 10 + q];
                acc[q].x = fmaf(af, wlv.x, fmaf(xf, wrv.x, acc[q].x));
                acc[q].y = fmaf(af, wlv.y, fmaf(xf, wrv.y, acc[q].y));
                acc[q].z = fmaf(af, wlv.z, fmaf(xf, wrv.z, acc[q].z));
                acc[q].w = fmaf(af, wlv.w, fmaf(xf, wrv.w, acc[q].w));
            }
        }
    }

    // log_softmax over the 40 accumulators
    float m = -1e30f;
#pragma unroll
    for (int q = 0; q < 10; ++q)
        m = fmaxf(m, fmaxf(fmaxf(acc[q].x, acc[q].y), fmaxf(acc[q].z, acc[q].w)));
    float ssum = 0.0f;
#pragma unroll
    for (int q = 0; q < 10; ++q)
        ssum += __expf(acc[q].x - m) + __expf(acc[q].y - m) +
                __expf(acc[q].z - m) + __expf(acc[q].w - m);
    float lse = m + __logf(ssum);

    float4* o = (float4*)(out + (size_t)n * C);  // n*160B, 16B-aligned
#pragma unroll
    for (int q = 0; q < 10; ++q) {
        float4 v;
        v.x = acc[q].x - lse;
        v.y = acc[q].y - lse;
        v.z = acc[q].z - lse;
        v.w = acc[q].w - lse;
        o[q] = v;
    }
}

extern "C" void kernel_launch(void* const* d_in, const int* in_sizes, int n_in,
                              void* d_out, int out_size, void* d_ws, size_t ws_size,
                              hipStream_t stream) {
    const float* x     = (const float*)d_in[0];
    const int*   index = (const int*)d_in[1];
    const float* wl    = (const float*)d_in[2];
    const float* bl    = (const float*)d_in[3];
    const float* wr    = (const float*)d_in[4];
    float* out = (float*)d_out;

    int nedges = in_sizes[1] / 2;
    const int* src = index;            // index[0, :]
    const int* dst = index + nedges;   // index[1, :]

    // Workspace layout: agg_sum [NODES*F] floats, deg [NODES] floats
    float* aggsum = (float*)d_ws;
    float* deg    = aggsum + (size_t)NODES * F;
    size_t zbytes = ((size_t)NODES * F + (size_t)NODES) * sizeof(float);
    hipMemsetAsync(d_ws, 0, zbytes, stream);

    int nblk = (nedges + 3) / 4;  // 4 edges (waves) per 256-thread block
    scatter_kernel<<<nblk, 256, 0, stream>>>(x, src, dst, aggsum, deg, nedges);

    node_kernel<<<(NODES + 255) / 256, 256, 0, stream>>>(x, aggsum, deg, wl, bl, wr, out);
}

// Round 2
// 400.531 us; speedup vs baseline: 1.3742x; 1.3742x over previous
//
#include <hip/hip_runtime.h>
#include <math.h>

constexpr int NODES = 100000;
constexpr int F = 64;      // features
constexpr int C = 40;      // classes

// ===========================================================================
// CSR-lite path: hist -> ticket offsets -> bin -> wave-per-node aggregate
// ===========================================================================

__global__ __launch_bounds__(256)
void hist_kernel(const int* __restrict__ dst, int* __restrict__ degi, int nedges) {
    int e = blockIdx.x * 256 + threadIdx.x;
    if (e >= nedges) return;
    int d = dst[e];
    if ((unsigned)d < (unsigned)NODES) atomicAdd(&degi[d], 1);
}

__global__ __launch_bounds__(256)
void offsets_kernel(const int* __restrict__ degi, int* __restrict__ gcount,
                    int* __restrict__ off, int* __restrict__ cursor) {
    int n = blockIdx.x * 256 + threadIdx.x;
    if (n >= NODES) return;
    int d = degi[n];
    int o = atomicAdd(gcount, d);   // disjoint contiguous regions, order arbitrary
    off[n] = o;
    cursor[n] = o;
}

__global__ __launch_bounds__(256)
void bin_kernel(const int* __restrict__ src, const int* __restrict__ dst,
                int* __restrict__ cursor, int* __restrict__ sorted_src, int nedges) {
    int e = blockIdx.x * 256 + threadIdx.x;
    if (e >= nedges) return;
    int s = src[e];
    int d = dst[e];
    if ((unsigned)s >= (unsigned)NODES || (unsigned)d >= (unsigned)NODES) return;
    int p = atomicAdd(&cursor[d], 1);
    sorted_src[p] = s;
}

// One wave per node, lane = feature. Gathers x rows for its incoming edges,
// writes the MEAN once (no atomics).
__global__ __launch_bounds__(256)
void aggregate_kernel(const float* __restrict__ x,
                      const int* __restrict__ sorted_src,
                      const int* __restrict__ off,
                      const int* __restrict__ degi,
                      float* __restrict__ aggmean) {
    int lane = threadIdx.x & 63;
    int n = blockIdx.x * 4 + (threadIdx.x >> 6);
    if (n >= NODES) return;
    int base = off[n];
    int cnt = degi[n];

    float acc = 0.0f;
    int j = 0;
    for (; j + 4 <= cnt; j += 4) {
        // same-address broadcast loads (one line request per wave)
        int s0 = sorted_src[base + j + 0];
        int s1 = sorted_src[base + j + 1];
        int s2 = sorted_src[base + j + 2];
        int s3 = sorted_src[base + j + 3];
        float v0 = x[(size_t)s0 * F + lane];
        float v1 = x[(size_t)s1 * F + lane];
        float v2 = x[(size_t)s2 * F + lane];
        float v3 = x[(size_t)s3 * F + lane];
        acc += v0 + v1 + v2 + v3;
    }
    for (; j < cnt; ++j) {
        int s = sorted_src[base + j];
        acc += x[(size_t)s * F + lane];
    }
    float inv = 1.0f / (float)max(cnt, 1);
    aggmean[(size_t)n * F + lane] = acc * inv;
}

// ===========================================================================
// Fallback (R1): atomic scatter, only used if ws_size too small
// ===========================================================================
__global__ __launch_bounds__(256)
void scatter_kernel(const float* __restrict__ x,
                    const int* __restrict__ src,
                    const int* __restrict__ dst,
                    float* __restrict__ aggsum,
                    float* __restrict__ deg,
                    int nedges) {
    int lane = threadIdx.x & 63;
    int e = blockIdx.x * 4 + (threadIdx.x >> 6);
    if (e >= nedges) return;
    int s = src[e];
    int d = dst[e];
    if ((unsigned)s >= (unsigned)NODES || (unsigned)d >= (unsigned)NODES) return;
    float v = x[(size_t)s * F + lane];
    atomicAdd(&aggsum[(size_t)d * F + lane], v);
    if (lane == 0) atomicAdd(&deg[d], 1.0f);
}

__global__ __launch_bounds__(256)
void meanify_kernel(float* __restrict__ aggsum, const float* __restrict__ deg) {
    int lane = threadIdx.x & 63;
    int n = blockIdx.x * 4 + (threadIdx.x >> 6);
    if (n >= NODES) return;
    float inv = 1.0f / fmaxf(deg[n], 1.0f);
    aggsum[(size_t)n * F + lane] *= inv;
}

// ===========================================================================
// Phase 2: out = aggmean @ Wl + b + x @ Wr, then log_softmax. Thread per node.
// ===========================================================================
__global__ __launch_bounds__(256)
void node_kernel(const float* __restrict__ x,
                 const float* __restrict__ aggmean,
                 const float* __restrict__ wl,
                 const float* __restrict__ bl,
                 const float* __restrict__ wr,
                 float* __restrict__ out) {
    __shared__ alignas(16) float sWl[F * C];
    __shared__ alignas(16) float sWr[F * C];
    __shared__ alignas(16) float sb[C];

    for (int i = threadIdx.x; i < F * C; i += 256) {
        sWl[i] = wl[i];
        sWr[i] = wr[i];
    }
    if (threadIdx.x < C) sb[threadIdx.x] = bl[threadIdx.x];
    __syncthreads();

    int n = blockIdx.x * 256 + threadIdx.x;
    if (n >= NODES) return;

    float4 acc[10];
    const float4* sb4 = (const float4*)sb;
#pragma unroll
    for (int q = 0; q < 10; ++q) acc[q] = sb4[q];

    const float4* xr  = (const float4*)(x       + (size_t)n * F);
    const float4* ar  = (const float4*)(aggmean + (size_t)n * F);
    const float4* wl4 = (const float4*)sWl;
    const float4* wr4 = (const float4*)sWr;

    for (int f4 = 0; f4 < F / 4; ++f4) {
        float4 xv = xr[f4];
        float4 av = ar[f4];
        float xs[4]  = {xv.x, xv.y, xv.z, xv.w};
        float as_[4] = {av.x, av.y, av.z, av.w};
#pragma unroll
        for (int j = 0; j < 4; ++j) {
            int f = f4 * 4 + j;
            float xf = xs[j];
            float af = as_[j];
#pragma unroll
            for (int q = 0; q < 10; ++q) {
                float4 wlv = wl4[f * 10 + q];
                float4 wrv = wr4[f * 10 + q];
                acc[q].x = fmaf(af, wlv.x, fmaf(xf, wrv.x, acc[q].x));
                acc[q].y = fmaf(af, wlv.y, fmaf(xf, wrv.y, acc[q].y));
                acc[q].z = fmaf(af, wlv.z, fmaf(xf, wrv.z, acc[q].z));
                acc[q].w = fmaf(af, wlv.w, fmaf(xf, wrv.w, acc[q].w));
            }
        }
    }

    float m = -1e30f;
#pragma unroll
    for (int q = 0; q < 10; ++q)
        m = fmaxf(m, fmaxf(fmaxf(acc[q].x, acc[q].y), fmaxf(acc[q].z, acc[q].w)));
    float ssum = 0.0f;
#pragma unroll
    for (int q = 0; q < 10; ++q)
        ssum += __expf(acc[q].x - m) + __expf(acc[q].y - m) +
                __expf(acc[q].z - m) + __expf(acc[q].w - m);
    float lse = m + __logf(ssum);

    float4* o = (float4*)(out + (size_t)n * C);
#pragma unroll
    for (int q = 0; q < 10; ++q) {
        float4 v;
        v.x = acc[q].x - lse;
        v.y = acc[q].y - lse;
        v.z = acc[q].z - lse;
        v.w = acc[q].w - lse;
        o[q] = v;
    }
}

extern "C" void kernel_launch(void* const* d_in, const int* in_sizes, int n_in,
                              void* d_out, int out_size, void* d_ws, size_t ws_size,
                              hipStream_t stream) {
    const float* x     = (const float*)d_in[0];
    const int*   index = (const int*)d_in[1];
    const float* wl    = (const float*)d_in[2];
    const float* bl    = (const float*)d_in[3];
    const float* wr    = (const float*)d_in[4];
    float* out = (float*)d_out;

    int nedges = in_sizes[1] / 2;
    const int* src = index;
    const int* dst = index + nedges;

    // --- CSR-lite workspace layout ---
    // [degi: NODES int][gcount: 1 int][off: NODES int][cursor: NODES int]
    // [sorted_src: E int][aggmean: NODES*F float]
    size_t need = (size_t)(3 * NODES + 1) * 4 + (size_t)nedges * 4
                + (size_t)NODES * F * 4;

    if (ws_size >= need) {
        int* degi       = (int*)d_ws;
        int* gcount     = degi + NODES;
        int* off        = gcount + 1;
        int* cursor     = off + NODES;
        int* sorted_src = cursor + NODES;
        float* aggmean  = (float*)(sorted_src + nedges);

        hipMemsetAsync(degi, 0, (size_t)(NODES + 1) * sizeof(int), stream);

        int eblk = (nedges + 255) / 256;
        int nblk = (NODES + 255) / 256;
        hist_kernel<<<eblk, 256, 0, stream>>>(dst, degi, nedges);
        offsets_kernel<<<nblk, 256, 0, stream>>>(degi, gcount, off, cursor);
        bin_kernel<<<eblk, 256, 0, stream>>>(src, dst, cursor, sorted_src, nedges);
        aggregate_kernel<<<(NODES + 3) / 4, 256, 0, stream>>>(
            x, sorted_src, off, degi, aggmean);
        node_kernel<<<nblk, 256, 0, stream>>>(x, aggmean, wl, bl, wr, out);
    } else {
        // Fallback: R1 atomic-scatter path (needs 25.64 MB)
        float* aggsum = (float*)d_ws;
        float* deg    = aggsum + (size_t)NODES * F;
        size_t zbytes = ((size_t)NODES * F + (size_t)NODES) * sizeof(float);
        hipMemsetAsync(d_ws, 0, zbytes, stream);

        int nblk4 = (nedges + 3) / 4;
        scatter_kernel<<<nblk4, 256, 0, stream>>>(x, src, dst, aggsum, deg, nedges);
        meanify_kernel<<<(NODES + 3) / 4, 256, 0, stream>>>(aggsum, deg);
        node_kernel<<<(NODES + 255) / 256, 256, 0, stream>>>(
            x, aggsum, wl, bl, wr, out);
    }
}